// Round 1
// baseline (84.618 us; speedup 1.0000x reference)
//
#include <hip/hip_runtime.h>
#include <hip/hip_fp16.h>

// MinEuclideanDistBlock: out[b,n] = min_w sum_c sqrt(max(||win||^2 + ||shp||^2 - 2*cross, 0))
// B=64, C=3, L=2048, N=256, S=64, W=1985. Strategy: bf16 MFMA 16x16x32 for cross,
// fp32 norms from the same bf16-rounded values, fused sqrt/sum/min epilogue.
// Grid 256 = (b=64) x (4 n-tiles of 64); block = 8 waves; wave tile 32w x 64n.

typedef float  v4f __attribute__((ext_vector_type(4)));
typedef short  v8s __attribute__((ext_vector_type(8)));
typedef unsigned short u16;
typedef unsigned int   u32;
typedef unsigned long long u64;

#define S_ 64
#define N_ 256
#define C_ 3
#define B_ 64
#define L_ 2048
#define W_ 1985
#define NCHUNK 530   // 8B chunks per shifted copy (covers padded elements, bank-skewed stride)
#define THREADS 512
#define WAVES 8

__device__ __forceinline__ u16 f2bf(float f) {
    u32 u = __builtin_bit_cast(u32, f);
    return (u16)((u + 0x7FFFu + ((u >> 16) & 1u)) >> 16);
}
__device__ __forceinline__ float bf2f(u16 b) {
    return __builtin_bit_cast(float, ((u32)b) << 16);
}

__global__ __launch_bounds__(THREADS, 2)
void shapelet_min_kernel(const float* __restrict__ x,
                         const float* __restrict__ shp,
                         float* __restrict__ out)
{
    __shared__ u64 xcopy[C_][4][NCHUNK];     // 50880 B: 4 shifted bf16 copies of x[b,c,:]
    __shared__ __half wsq[C_][L_];           // 12288 B: sliding window sq-norms (fp16)
    __shared__ float red[WAVES][64];         // 2048 B : cross-wave min reduction

    const int tid  = threadIdx.x;
    const int wave = tid >> 6;
    const int lane = tid & 63;
    const int m    = lane & 15;      // MFMA row/col within 16
    const int q    = lane >> 4;      // quad id 0..3
    const int b    = blockIdx.x >> 2;
    const int n0   = (blockIdx.x & 3) << 6;

    //=== Phase A: stage this block's shapelet tile (bf16) into scratch (aliases xcopy) ===
    u16* scratch = (u16*)&xcopy[0][0][0];    // [C_][64][72] u16 = 27648 B  (72 = 64 + pad8)
    #pragma unroll
    for (int k = 0; k < 6; ++k) {
        int idx = tid + k * THREADS;         // 3072 float4-groups: (c, n, sq)
        int sq = idx & 15;
        int n  = (idx >> 4) & 63;
        int c  = idx >> 10;
        v4f v = *(const v4f*)(shp + ((size_t)(c * N_ + n0 + n) * S_ + (sq << 2)));
        u64 pk = (u64)f2bf(v[0]) | ((u64)f2bf(v[1]) << 16)
               | ((u64)f2bf(v[2]) << 32) | ((u64)f2bf(v[3]) << 48);
        *(u64*)(scratch + ((c * 64 + n) * 72 + (sq << 2))) = pk;
    }
    __syncthreads();

    // B fragments -> registers (loop-invariant over w) + shapelet norms per lane's n
    v8s bfr[C_][4][2];
    float ssq[C_][4];
    #pragma unroll
    for (int c = 0; c < C_; ++c) {
        #pragma unroll
        for (int nt = 0; nt < 4; ++nt) {
            float sacc = 0.f;
            #pragma unroll
            for (int h = 0; h < 2; ++h) {
                v8s f = *(const v8s*)(scratch + ((c * 64 + nt * 16 + m) * 72 + h * 32 + q * 8));
                bfr[c][nt][h] = f;
                #pragma unroll
                for (int j = 0; j < 8; ++j) {
                    float e = bf2f((u16)f[j]);
                    sacc += e * e;
                }
            }
            sacc += __shfl_xor(sacc, 16);
            sacc += __shfl_xor(sacc, 32);
            ssq[c][nt] = sacc;               // per-lane n = nt*16 + m
        }
    }
    __syncthreads();

    //=== Phase B: build 4 shifted bf16 copies of x[b] (copy r = x[r:], b64-chunked) ===
    {
        const float* xb = x + (size_t)b * (C_ * L_);
        #pragma unroll
        for (int k = 0; k < 4; ++k) {
            int gi = tid + k * THREADS;
            if (gi < C_ * NCHUNK) {          // 1590 groups of 4 elements
                int c = gi / NCHUNK;
                int t = gi - c * NCHUNK;
                int e = t << 2;
                float f[4];
                if (e + 3 < L_) {
                    v4f v = *(const v4f*)(xb + c * L_ + e);
                    f[0] = v[0]; f[1] = v[1]; f[2] = v[2]; f[3] = v[3];
                } else {
                    #pragma unroll
                    for (int i = 0; i < 4; ++i)
                        f[i] = (e + i < L_) ? xb[c * L_ + e + i] : 0.f;
                }
                u16 u[4];
                #pragma unroll
                for (int i = 0; i < 4; ++i) u[i] = f2bf(f[i]);
                #pragma unroll
                for (int r = 0; r < 4; ++r) {
                    u16* cp = (u16*)&xcopy[c][r][0];
                    #pragma unroll
                    for (int i = 0; i < 4; ++i) {
                        int pos = e + i - r;          // element j=e+i sits at index j-r in copy r
                        if (pos >= 0) cp[pos] = u[i];
                    }
                }
            }
        }
    }
    __syncthreads();

    //=== win_sq: sliding sum of squares from bf16 copy 0, fp32 accumulate, fp16 store ===
    #pragma unroll
    for (int c = 0; c < C_; ++c) {
        const u64* cp0 = &xcopy[c][0][0];
        float e[68];
        #pragma unroll
        for (int kk = 0; kk < 17; ++kk) {
            u64 ch = cp0[tid + kk];
            e[kk * 4 + 0] = bf2f((u16)(ch));
            e[kk * 4 + 1] = bf2f((u16)(ch >> 16));
            e[kk * 4 + 2] = bf2f((u16)(ch >> 32));
            e[kk * 4 + 3] = bf2f((u16)(ch >> 48));
        }
        float s0 = 0.f;
        #pragma unroll
        for (int i = 0; i < 64; ++i) s0 += e[i] * e[i];
        float s1 = s0 - e[0] * e[0] + e[64] * e[64];
        float s2 = s1 - e[1] * e[1] + e[65] * e[65];
        float s3 = s2 - e[2] * e[2] + e[66] * e[66];
        union { u64 u; __half h[4]; } hp;
        hp.h[0] = __float2half(s0); hp.h[1] = __float2half(s1);
        hp.h[2] = __float2half(s2); hp.h[3] = __float2half(s3);
        *(u64*)&wsq[c][tid << 2] = hp.u;
    }
    __syncthreads();

    //=== Main loop: 8 iters x (wave tile 32w x 64n), channels fused before min ===
    float mins[4] = {1e30f, 1e30f, 1e30f, 1e30f};
    const int r = m & 3;

    #pragma unroll 1
    for (int it = 0; it < 8; ++it) {
        const int wbase = it * 256 + wave * 32;
        if (wbase >= W_) continue;           // only wave7 @ it7 is fully invalid

        float sums[2][4][4];
        #pragma unroll
        for (int mt = 0; mt < 2; ++mt)
            #pragma unroll
            for (int nt = 0; nt < 4; ++nt)
                #pragma unroll
                for (int g = 0; g < 4; ++g) sums[mt][nt][g] = 0.f;

        #pragma unroll
        for (int c = 0; c < C_; ++c) {
            // A-fragments: lane reads 8 contiguous bf16 via two aligned b64 from copy (m&3)
            v8s afr[2][2];
            #pragma unroll
            for (int mt = 0; mt < 2; ++mt) {
                #pragma unroll
                for (int h = 0; h < 2; ++h) {
                    int p0 = wbase + mt * 16 + m + h * 32 + q * 8;
                    int T  = (p0 - r) >> 2;
                    const u64* cp = &xcopy[c][r][0];
                    union { u64 u[2]; v8s v; } tmp;
                    tmp.u[0] = cp[T];
                    tmp.u[1] = cp[T + 1];
                    afr[mt][h] = tmp.v;
                }
            }
            v4f acc[2][4];
            #pragma unroll
            for (int mt = 0; mt < 2; ++mt)
                #pragma unroll
                for (int nt = 0; nt < 4; ++nt)
                    acc[mt][nt] = (v4f){0.f, 0.f, 0.f, 0.f};

            #pragma unroll
            for (int h = 0; h < 2; ++h)
                #pragma unroll
                for (int mt = 0; mt < 2; ++mt)
                    #pragma unroll
                    for (int nt = 0; nt < 4; ++nt)
                        acc[mt][nt] = __builtin_amdgcn_mfma_f32_16x16x32_bf16(
                            afr[mt][h], bfr[c][nt][h], acc[mt][nt], 0, 0, 0);

            // epilogue: d = sqrt(max(wsq + ssq - 2*cross, 0)); accumulate over channels
            #pragma unroll
            for (int mt = 0; mt < 2; ++mt) {
                union { u64 u; __half h4[4]; } wq;
                wq.u = *(const u64*)&wsq[c][wbase + mt * 16 + q * 4];
                float wv[4];
                #pragma unroll
                for (int g = 0; g < 4; ++g) wv[g] = __half2float(wq.h4[g]);
                #pragma unroll
                for (int nt = 0; nt < 4; ++nt) {
                    #pragma unroll
                    for (int g = 0; g < 4; ++g) {
                        float d2 = wv[g] + ssq[c][nt] - 2.f * acc[mt][nt][g];
                        d2 = fmaxf(d2, 0.f);
                        sums[mt][nt][g] += __builtin_amdgcn_sqrtf(d2);
                    }
                }
            }
        }
        // fold into running min over w (mask invalid padded windows)
        #pragma unroll
        for (int mt = 0; mt < 2; ++mt) {
            #pragma unroll
            for (int g = 0; g < 4; ++g) {
                int w = wbase + mt * 16 + q * 4 + g;
                bool ok = (w < W_);
                #pragma unroll
                for (int nt = 0; nt < 4; ++nt) {
                    float vv = ok ? sums[mt][nt][g] : 1e30f;
                    mins[nt] = fminf(mins[nt], vv);
                }
            }
        }
    }

    //=== Reductions: across quads (same n, different w-rows), then across waves ===
    #pragma unroll
    for (int nt = 0; nt < 4; ++nt) {
        mins[nt] = fminf(mins[nt], __shfl_xor(mins[nt], 16));
        mins[nt] = fminf(mins[nt], __shfl_xor(mins[nt], 32));
    }
    if (lane < 16) {
        #pragma unroll
        for (int nt = 0; nt < 4; ++nt) red[wave][nt * 16 + lane] = mins[nt];
    }
    __syncthreads();
    if (tid < 64) {
        float v = red[0][tid];
        #pragma unroll
        for (int wv = 1; wv < WAVES; ++wv) v = fminf(v, red[wv][tid]);
        out[(size_t)b * N_ + n0 + tid] = v;
    }
}

extern "C" void kernel_launch(void* const* d_in, const int* in_sizes, int n_in,
                              void* d_out, int out_size, void* d_ws, size_t ws_size,
                              hipStream_t stream) {
    const float* x   = (const float*)d_in[0];   // (64, 3, 2048) fp32
    const float* shp = (const float*)d_in[1];   // (3, 256, 64) fp32
    float* out       = (float*)d_out;           // (64, 1, 256) fp32
    hipLaunchKernelGGL(shapelet_min_kernel, dim3(256), dim3(THREADS), 0, stream,
                       x, shp, out);
}